// Round 1
// baseline (288.363 us; speedup 1.0000x reference)
//
#include <hip/hip_runtime.h>

typedef __attribute__((ext_vector_type(8))) short  short8;
typedef __attribute__((ext_vector_type(4))) short  short4v;
typedef __attribute__((ext_vector_type(4))) float  floatx4;

__device__ inline short f2bf(float f) {
    union { float f; unsigned u; } v; v.f = f;
    unsigned r = v.u + 0x7fffu + ((v.u >> 16) & 1u);
    return (short)(r >> 16);
}

typedef const __attribute__((address_space(1))) unsigned int* gp1_t;
typedef __attribute__((address_space(3))) unsigned int* lp3_t;

__device__ __attribute__((always_inline)) inline void gl_lds16(const short* g, short* l) {
    __builtin_amdgcn_global_load_lds((gp1_t)g, (lp3_t)l, 16, 0, 0);
}

#define MFMA_BF16 __builtin_amdgcn_mfma_f32_16x16x32_bf16

// ---------------------------------------------------------------------------
// m97-style GEMM-BT core: C[128][128], 256 thr / 4 waves (2x2), BK=64.
// (kept for sqk_gemm / pv_gemm this round)
// ---------------------------------------------------------------------------
__device__ __attribute__((always_inline)) inline void gemm_bt_core(
    const short* __restrict__ Ag, const short* __restrict__ Bg,
    int lda, int ldb, int kmax,
    short* As, short* Bs, floatx4 acc[4][4])
{
    const int t    = threadIdx.x;
    const int srow = t >> 3;
    const int scol = (t & 7) * 8;
    const int lane = t & 63;
    const int wid  = t >> 6;
    const int wx   = wid & 1, wy = wid >> 1;
    const int lm   = lane & 15, lq = lane >> 4;

    for (int k0 = 0; k0 < kmax; k0 += 64) {
        __syncthreads();
#pragma unroll
        for (int i = 0; i < 4; ++i) {
            gl_lds16(Ag + (size_t)(i * 32 + srow) * lda + k0 + scol,
                     As + (i * 32 + srow) * 64 + scol);
            gl_lds16(Bg + (size_t)(i * 32 + srow) * ldb + k0 + scol,
                     Bs + (i * 32 + srow) * 64 + scol);
        }
        __syncthreads();

#pragma unroll
        for (int ks = 0; ks < 2; ++ks) {
            short8 af[4], bfr[4];
#pragma unroll
            for (int mi = 0; mi < 4; ++mi)
                af[mi] = *(const short8*)(As + (wy * 64 + mi * 16 + lm) * 64 + ks * 32 + lq * 8);
#pragma unroll
            for (int ni = 0; ni < 4; ++ni)
                bfr[ni] = *(const short8*)(Bs + (wx * 64 + ni * 16 + lm) * 64 + ks * 32 + lq * 8);
#pragma unroll
            for (int mi = 0; mi < 4; ++mi)
#pragma unroll
                for (int ni = 0; ni < 4; ++ni)
                    acc[mi][ni] = MFMA_BF16(af[mi], bfr[ni], acc[mi][ni], 0, 0, 0);
        }
    }
}

// ---------------------------------------------------------------------------
// Kernel 0: fp32 -> bf16 cast of x and W's; also zeros lsum (atomic target).
// ---------------------------------------------------------------------------
__global__ void cast_all(const float* __restrict__ x,
                         const float* __restrict__ Wq,
                         const float* __restrict__ Wk,
                         const float* __restrict__ Wv,
                         short* __restrict__ xb, short* __restrict__ wb,
                         float* __restrict__ lsum)
{
    size_t v = (size_t)blockIdx.x * 256 + threadIdx.x;
    const float* src; short* dst; size_t off;
    if (v < 2097152)      { src = x;  dst = xb;           off = v; }
    else if (v < 2359296) { src = Wq; dst = wb;           off = v - 2097152; }
    else if (v < 2621440) { src = Wk; dst = wb + 1048576; off = v - 2359296; }
    else if (v < 2883584) { src = Wv; dst = wb + 2097152; off = v - 2621440; }
    else if (v < 2885632) {                               // zero lsum (8192 f32)
        floatx4 z = {0.f, 0.f, 0.f, 0.f};
        ((floatx4*)lsum)[v - 2883584] = z;
        return;
    } else return;
    floatx4 vv = ((const floatx4*)src)[off];
    short4v s;
#pragma unroll
    for (int e = 0; e < 4; ++e) s[e] = f2bf(vv[e]);
    ((short4v*)dst)[off] = s;
}

// ---------------------------------------------------------------------------
// Kernel 1 (new): QKV projection as ONE 8192x3072x1024 GEMM-BT.
// 256x256 tile, BK=64, 8 waves (2Mx4N, 128x64 each), 128 KiB LDS (2 K-tile
// slots, double-buffered). Pipelined 4-phase-per-K-tile schedule:
//   P0: ds_read af(lo)+bf(lo) | bar | MFMA q(0,lo) | bar
//   P1: ds_read bf(hi)        | bar | MFMA q(0,hi) | bar
//   P2: ds_read af(hi)        | bar | MFMA q(1,hi) | bar
//   P3: issue 8x global_load_lds for K-tile kt+2 into THIS slot (its last
//       ds_read was P2, barrier-separated -> race-free) | MFMA q(1,lo) |
//       s_waitcnt vmcnt(8) (kt+1 landed; kt+2 stays in flight) | bar
// LDS swizzle (T2): 16B col-slot ^= (row&7), applied to the GLOBAL source of
// global_load_lds (dest stays lane-linear) and to the ds_read address.
// ---------------------------------------------------------------------------
template<int MODE>   // 0: stage kt+2 + vmcnt(8); 1: no stage + vmcnt(0); 2: tail
__device__ __attribute__((always_inline)) inline void ktile4(
    short* As, short* Bs,
    const short* __restrict__ Ag, const short* __restrict__ Bg, int sk0,
    int srow, int scl, int scg, int aB, int bB, int c0, int c1,
    floatx4 acc[8][4])
{
    short8 af[4][2], bf[4][2];
    // ---- P0
#pragma unroll
    for (int mi = 0; mi < 4; ++mi) {
        af[mi][0] = *(const short8*)(As + aB + mi * 1024 + c0);
        af[mi][1] = *(const short8*)(As + aB + mi * 1024 + c1);
    }
#pragma unroll
    for (int ni = 0; ni < 2; ++ni) {
        bf[ni][0] = *(const short8*)(Bs + bB + ni * 1024 + c0);
        bf[ni][1] = *(const short8*)(Bs + bB + ni * 1024 + c1);
    }
    __builtin_amdgcn_s_barrier();
    asm volatile("s_waitcnt lgkmcnt(0)" ::: "memory");
    __builtin_amdgcn_s_setprio(1);
#pragma unroll
    for (int mi = 0; mi < 4; ++mi)
#pragma unroll
        for (int ni = 0; ni < 2; ++ni) {
            acc[mi][ni] = MFMA_BF16(af[mi][0], bf[ni][0], acc[mi][ni], 0, 0, 0);
            acc[mi][ni] = MFMA_BF16(af[mi][1], bf[ni][1], acc[mi][ni], 0, 0, 0);
        }
    __builtin_amdgcn_s_setprio(0);
    __builtin_amdgcn_s_barrier();
    // ---- P1
#pragma unroll
    for (int ni = 2; ni < 4; ++ni) {
        bf[ni][0] = *(const short8*)(Bs + bB + ni * 1024 + c0);
        bf[ni][1] = *(const short8*)(Bs + bB + ni * 1024 + c1);
    }
    __builtin_amdgcn_s_barrier();
    asm volatile("s_waitcnt lgkmcnt(0)" ::: "memory");
    __builtin_amdgcn_s_setprio(1);
#pragma unroll
    for (int mi = 0; mi < 4; ++mi)
#pragma unroll
        for (int ni = 2; ni < 4; ++ni) {
            acc[mi][ni] = MFMA_BF16(af[mi][0], bf[ni][0], acc[mi][ni], 0, 0, 0);
            acc[mi][ni] = MFMA_BF16(af[mi][1], bf[ni][1], acc[mi][ni], 0, 0, 0);
        }
    __builtin_amdgcn_s_setprio(0);
    __builtin_amdgcn_s_barrier();
    // ---- P2
#pragma unroll
    for (int mi = 0; mi < 4; ++mi) {
        af[mi][0] = *(const short8*)(As + aB + 4096 + mi * 1024 + c0);
        af[mi][1] = *(const short8*)(As + aB + 4096 + mi * 1024 + c1);
    }
    __builtin_amdgcn_s_barrier();
    asm volatile("s_waitcnt lgkmcnt(0)" ::: "memory");
    __builtin_amdgcn_s_setprio(1);
#pragma unroll
    for (int mi = 0; mi < 4; ++mi)
#pragma unroll
        for (int ni = 2; ni < 4; ++ni) {
            acc[4 + mi][ni] = MFMA_BF16(af[mi][0], bf[ni][0], acc[4 + mi][ni], 0, 0, 0);
            acc[4 + mi][ni] = MFMA_BF16(af[mi][1], bf[ni][1], acc[4 + mi][ni], 0, 0, 0);
        }
    __builtin_amdgcn_s_setprio(0);
    __builtin_amdgcn_s_barrier();
    // ---- P3
    if (MODE == 0) {
#pragma unroll
        for (int i = 0; i < 4; ++i)
            gl_lds16(Ag + (size_t)(i * 64 + srow) * 1024 + sk0 + scg,
                     As + (i * 64 + srow) * 64 + scl);
#pragma unroll
        for (int i = 0; i < 4; ++i)
            gl_lds16(Bg + (size_t)(i * 64 + srow) * 1024 + sk0 + scg,
                     Bs + (i * 64 + srow) * 64 + scl);
    }
    __builtin_amdgcn_s_setprio(1);
#pragma unroll
    for (int mi = 0; mi < 4; ++mi)
#pragma unroll
        for (int ni = 0; ni < 2; ++ni) {
            acc[4 + mi][ni] = MFMA_BF16(af[mi][0], bf[ni][0], acc[4 + mi][ni], 0, 0, 0);
            acc[4 + mi][ni] = MFMA_BF16(af[mi][1], bf[ni][1], acc[4 + mi][ni], 0, 0, 0);
        }
    __builtin_amdgcn_s_setprio(0);
    if (MODE == 0)      asm volatile("s_waitcnt vmcnt(8)" ::: "memory");
    else if (MODE == 1) asm volatile("s_waitcnt vmcnt(0)" ::: "memory");
    __builtin_amdgcn_s_barrier();
}

__global__ __launch_bounds__(512, 2) void qkv_gemm8(
    const short* __restrict__ xb, const short* __restrict__ wb,
    short* __restrict__ qb, short* __restrict__ kb, short* __restrict__ vt)
{
    __shared__ short lds[65536];   // 128 KiB: [slot0 A|B][slot1 A|B]

    // XCD-aware swizzle: 384 blocks, 384 % 8 == 0 -> simple bijection.
    const int orig = blockIdx.x;
    const int tile = (orig & 7) * 48 + (orig >> 3);
    const int mt = tile & 31;          // tile % 32  -> m tile (A panel)
    const int nt = tile >> 5;          // tile / 32  -> n tile (B panel, 0..11)
    const int m0 = mt * 256;

    const short* Ag = xb + (size_t)m0 * 1024;
    const short* Bg = wb + (size_t)(nt * 256) * 1024;

    const int t    = threadIdx.x;
    const int lane = t & 63;
    const int wid  = t >> 6;           // 0..7
    const int wy   = wid >> 2, wx = wid & 3;
    const int lm   = lane & 15, lq = lane >> 4;

    // staging: thread covers rows {i*64 + (t>>3)}, 16B col-slot (t&7).
    const int srow = t >> 3;
    const int scl  = (t & 7) * 8;                     // LDS col (linear!)
    const int scg  = ((t & 7) ^ (srow & 7)) * 8;      // global col (pre-swizzled)

    // ds_read swizzled col offsets: slot (4*ks+lq) ^ (row&7); row&7 == lm&7.
    const int c0 = (lq ^ (lm & 7)) * 8;
    const int c1 = ((4 + lq) ^ (lm & 7)) * 8;
    const int aB = (wy * 128 + lm) * 64;
    const int bB = (wx * 64 + lm) * 64;

    floatx4 acc[8][4];
    floatx4 zero = {0.f, 0.f, 0.f, 0.f};
#pragma unroll
    for (int i = 0; i < 8; ++i)
#pragma unroll
        for (int j = 0; j < 4; ++j) acc[i][j] = zero;

    short* A0 = lds;          short* B0 = lds + 16384;
    short* A1 = lds + 32768;  short* B1 = lds + 49152;

    // prologue: stage K-tiles 0 (slot0) and 1 (slot1); wait only for K-tile 0.
#pragma unroll
    for (int i = 0; i < 4; ++i) {
        gl_lds16(Ag + (size_t)(i * 64 + srow) * 1024 + scg,      A0 + (i * 64 + srow) * 64 + scl);
        gl_lds16(Bg + (size_t)(i * 64 + srow) * 1024 + scg,      B0 + (i * 64 + srow) * 64 + scl);
    }
#pragma unroll
    for (int i = 0; i < 4; ++i) {
        gl_lds16(Ag + (size_t)(i * 64 + srow) * 1024 + 64 + scg, A1 + (i * 64 + srow) * 64 + scl);
        gl_lds16(Bg + (size_t)(i * 64 + srow) * 1024 + 64 + scg, B1 + (i * 64 + srow) * 64 + scl);
    }
    asm volatile("s_waitcnt vmcnt(8)" ::: "memory");
    __builtin_amdgcn_s_barrier();

    // main loop: K = 1024 -> 16 K-tiles; kt pair per iteration (static slots).
#pragma unroll 1
    for (int k2 = 0; k2 < 7; ++k2) {
        const int kk = k2 * 128;
        ktile4<0>(A0, B0, Ag, Bg, kk + 128, srow, scl, scg, aB, bB, c0, c1, acc);
        ktile4<0>(A1, B1, Ag, Bg, kk + 192, srow, scl, scg, aB, bB, c0, c1, acc);
    }
    ktile4<1>(A0, B0, Ag, Bg, 0, srow, scl, scg, aB, bB, c0, c1, acc);  // kt=14
    ktile4<2>(A1, B1, Ag, Bg, 0, srow, scl, scg, aB, bB, c0, c1, acc);  // kt=15

    // epilogue: rows m0 + wy*128 + mi*16 + lq*4 + r; cols nt*256 + wx*64 + ni*16 + lm
    const int nglob = nt * 256;
    const int which = nglob >> 10;          // 0:Q 1:K 2:V (uniform per block)
    const int ncol  = (nglob & 1023) + wx * 64;
#pragma unroll
    for (int mi = 0; mi < 8; ++mi)
#pragma unroll
        for (int r = 0; r < 4; ++r) {
            const int row = m0 + wy * 128 + mi * 16 + lq * 4 + r;
#pragma unroll
            for (int ni = 0; ni < 4; ++ni) {
                const int col = ncol + ni * 16 + lm;
                const short bv = f2bf(acc[mi][ni][r]);
                if (which == 2) {
                    const int bb = row >> 11, tt = row & 2047;
                    vt[((size_t)bb * 1024 + col) * 2048 + tt] = bv;
                } else if (which == 1) {
                    kb[(size_t)row * 1024 + col] = bv;
                } else {
                    qb[(size_t)row * 1024 + col] = bv;
                }
            }
        }
}

// ---------------------------------------------------------------------------
// Kernel 2: fused S = QK^T*scale -> P = exp(S) (bf16, no-max) + causal mask
// + atomic row sums. grid (136 packed (i,j) j<=i, 4 b).
// ---------------------------------------------------------------------------
__global__ __launch_bounds__(256, 3) void sqk_gemm(
    const short* __restrict__ qb, const short* __restrict__ kb,
    short* __restrict__ P, float* __restrict__ lsum)
{
    int idx = blockIdx.x;
    int i = 0;
    while ((i + 1) * (i + 2) / 2 <= idx) ++i;     // decode packed (i,j)
    const int j = idx - i * (i + 1) / 2;
    const int b = blockIdx.y;

    __shared__ short As[128 * 64];
    __shared__ short Bs[128 * 64];

    floatx4 acc[4][4];
    floatx4 zero = {0.f, 0.f, 0.f, 0.f};
#pragma unroll
    for (int a = 0; a < 4; ++a)
#pragma unroll
        for (int c = 0; c < 4; ++c) acc[a][c] = zero;

    gemm_bt_core(qb + ((size_t)(b * 2048 + i * 128)) * 1024,
                 kb + ((size_t)(b * 2048 + j * 128)) * 1024,
                 1024, 1024, 1024, As, Bs, acc);

    const float sscl = 0.03125f * 1.44269504089f;   // C^-0.5 * log2(e)
    const bool  diag = (i == j);
    const int lane = threadIdx.x & 63, wid = threadIdx.x >> 6;
    const int wx = wid & 1, wy = wid >> 1, lm = lane & 15, lq = lane >> 4;

#pragma unroll
    for (int mi = 0; mi < 4; ++mi)
#pragma unroll
        for (int r = 0; r < 4; ++r) {
            const int lrow = wy * 64 + mi * 16 + lq * 4 + r;      // 0..127
            const int grow = i * 128 + lrow;
            short* prow = P + ((size_t)b * 2048 + grow) * 2048 + j * 128;
            float rsum = 0.f;
#pragma unroll
            for (int ni = 0; ni < 4; ++ni) {
                const int lcol = wx * 64 + ni * 16 + lm;
                float p = exp2f(acc[mi][ni][r] * sscl);
                if (diag && lcol > lrow) p = 0.f;                 // causal
                rsum += p;
                prow[lcol] = f2bf(p);
            }
#pragma unroll
            for (int off = 1; off < 16; off <<= 1) rsum += __shfl_xor(rsum, off);
            if (lm == 0) atomicAdd(lsum + b * 2048 + grow, rsum);
        }
}

// ---------------------------------------------------------------------------
// Kernel 3: O = (P V) / l. Causal-balanced pairs (i, 15-i).
// ---------------------------------------------------------------------------
__global__ __launch_bounds__(256, 3) void pv_gemm(
    const short* __restrict__ P, const short* __restrict__ vt,
    const float* __restrict__ lsum, float* __restrict__ out)
{
    const int x  = blockIdx.x;     // 64-wide d tile
    const int pr = blockIdx.y;     // pair id
    const int b  = blockIdx.z;
    const int n0 = x * 64;

    __shared__ short As[128 * 64];
    __shared__ short Bs[64 * 64];

    const int t    = threadIdx.x;
    const int srow = t >> 3;
    const int scol = (t & 7) * 8;
    const int lane = t & 63;
    const int wid  = t >> 6;
    const int wx   = wid & 1, wy = wid >> 1;
    const int lm   = lane & 15, lq = lane >> 4;

    const short* Bg = vt + ((size_t)b * 1024 + n0) * 2048;

#pragma unroll
    for (int phase = 0; phase < 2; ++phase) {
        const int i    = phase ? (15 - pr) : pr;
        const int kmax = (i + 1) * 128;
        const short* Ag = P + ((size_t)b * 2048 + i * 128) * 2048;

        floatx4 acc[4][2];
        floatx4 zero = {0.f, 0.f, 0.f, 0.f};
#pragma unroll
        for (int a = 0; a < 4; ++a)
#pragma unroll
            for (int c = 0; c < 2; ++c) acc[a][c] = zero;

        for (int k0 = 0; k0 < kmax; k0 += 64) {
            __syncthreads();
#pragma unroll
            for (int q = 0; q < 4; ++q)
                gl_lds16(Ag + (size_t)(q * 32 + srow) * 2048 + k0 + scol,
                         As + (q * 32 + srow) * 64 + scol);
#pragma unroll
            for (int q = 0; q < 2; ++q)
                gl_lds16(Bg + (size_t)(q * 32 + srow) * 2048 + k0 + scol,
                         Bs + (q * 32 + srow) * 64 + scol);
            __syncthreads();

#pragma unroll
            for (int ks = 0; ks < 2; ++ks) {
                short8 af[4], bfr[2];
#pragma unroll
                for (int mi = 0; mi < 4; ++mi)
                    af[mi] = *(const short8*)(As + (wy * 64 + mi * 16 + lm) * 64 + ks * 32 + lq * 8);
#pragma unroll
                for (int ni = 0; ni < 2; ++ni)
                    bfr[ni] = *(const short8*)(Bs + (wx * 32 + ni * 16 + lm) * 64 + ks * 32 + lq * 8);
#pragma unroll
                for (int mi = 0; mi < 4; ++mi)
#pragma unroll
                    for (int ni = 0; ni < 2; ++ni)
                        acc[mi][ni] = MFMA_BF16(af[mi], bfr[ni], acc[mi][ni], 0, 0, 0);
            }
        }

#pragma unroll
        for (int mi = 0; mi < 4; ++mi)
#pragma unroll
            for (int r = 0; r < 4; ++r) {
                const int grow = b * 2048 + i * 128 + wy * 64 + mi * 16 + lq * 4 + r;
                const float li = 1.0f / lsum[grow];
#pragma unroll
                for (int ni = 0; ni < 2; ++ni)
                    out[(size_t)grow * 1024 + n0 + wx * 32 + ni * 16 + lm] =
                        acc[mi][ni][r] * li;
            }
    }
}

// ---------------------------------------------------------------------------
extern "C" void kernel_launch(void* const* d_in, const int* in_sizes, int n_in,
                              void* d_out, int out_size, void* d_ws, size_t ws_size,
                              hipStream_t stream)
{
    (void)in_sizes; (void)n_in; (void)out_size; (void)ws_size;
    const float* x  = (const float*)d_in[0];
    const float* Wq = (const float*)d_in[1];
    const float* Wk = (const float*)d_in[2];
    const float* Wv = (const float*)d_in[3];
    float* out = (float*)d_out;

    char* base = (char*)d_ws;
    short* xb   = (short*)(base);                       // 16 MB
    short* wb   = (short*)(base + 16777216);            //  6 MB
    short* qb   = (short*)(base + 23068672);            // 16 MB
    short* kb   = (short*)(base + 39845888);            // 16 MB
    short* vt   = (short*)(base + 56623104);            // 16 MB  [b][d][t]
    short* P    = (short*)(base + 73400320);            // 33.6 MB [b][q][k]
    float* lsum = (float*)(base + 107954176);           // 32 KB

    cast_all<<<11272, 256, 0, stream>>>(x, Wq, Wk, Wv, xb, wb, lsum);
    qkv_gemm8<<<dim3(384), 512, 0, stream>>>(xb, wb, qb, kb, vt);
    sqk_gemm<<<dim3(136, 4), 256, 0, stream>>>(qb, kb, P, lsum);
    pv_gemm<<<dim3(16, 8, 4), 256, 0, stream>>>(P, vt, lsum, out);
}

// Round 2
// 282.518 us; speedup vs baseline: 1.0207x; 1.0207x over previous
//
#include <hip/hip_runtime.h>

typedef __attribute__((ext_vector_type(8))) short  short8;
typedef __attribute__((ext_vector_type(4))) short  short4v;
typedef __attribute__((ext_vector_type(4))) float  floatx4;

__device__ inline short f2bf(float f) {
    union { float f; unsigned u; } v; v.f = f;
    unsigned r = v.u + 0x7fffu + ((v.u >> 16) & 1u);
    return (short)(r >> 16);
}

typedef const __attribute__((address_space(1))) unsigned int* gp1_t;
typedef __attribute__((address_space(3))) unsigned int* lp3_t;

__device__ __attribute__((always_inline)) inline void gl_lds16(const short* g, short* l) {
    __builtin_amdgcn_global_load_lds((gp1_t)g, (lp3_t)l, 16, 0, 0);
}

#define MFMA_BF16 __builtin_amdgcn_mfma_f32_16x16x32_bf16

// ---------------------------------------------------------------------------
// m97-style GEMM-BT core: C[128][128], 256 thr / 4 waves (2x2), BK=64.
// (used by sqk_gemm / pv_gemm)
// ---------------------------------------------------------------------------
__device__ __attribute__((always_inline)) inline void gemm_bt_core(
    const short* __restrict__ Ag, const short* __restrict__ Bg,
    int lda, int ldb, int kmax,
    short* As, short* Bs, floatx4 acc[4][4])
{
    const int t    = threadIdx.x;
    const int srow = t >> 3;
    const int scol = (t & 7) * 8;
    const int lane = t & 63;
    const int wid  = t >> 6;
    const int wx   = wid & 1, wy = wid >> 1;
    const int lm   = lane & 15, lq = lane >> 4;

    for (int k0 = 0; k0 < kmax; k0 += 64) {
        __syncthreads();
#pragma unroll
        for (int i = 0; i < 4; ++i) {
            gl_lds16(Ag + (size_t)(i * 32 + srow) * lda + k0 + scol,
                     As + (i * 32 + srow) * 64 + scol);
            gl_lds16(Bg + (size_t)(i * 32 + srow) * ldb + k0 + scol,
                     Bs + (i * 32 + srow) * 64 + scol);
        }
        __syncthreads();

#pragma unroll
        for (int ks = 0; ks < 2; ++ks) {
            short8 af[4], bfr[4];
#pragma unroll
            for (int mi = 0; mi < 4; ++mi)
                af[mi] = *(const short8*)(As + (wy * 64 + mi * 16 + lm) * 64 + ks * 32 + lq * 8);
#pragma unroll
            for (int ni = 0; ni < 4; ++ni)
                bfr[ni] = *(const short8*)(Bs + (wx * 64 + ni * 16 + lm) * 64 + ks * 32 + lq * 8);
#pragma unroll
            for (int mi = 0; mi < 4; ++mi)
#pragma unroll
                for (int ni = 0; ni < 4; ++ni)
                    acc[mi][ni] = MFMA_BF16(af[mi], bfr[ni], acc[mi][ni], 0, 0, 0);
        }
    }
}

// ---------------------------------------------------------------------------
// Kernel 0: fp32 -> bf16 cast of x and W's; also zeros lsum (atomic target).
// ---------------------------------------------------------------------------
__global__ void cast_all(const float* __restrict__ x,
                         const float* __restrict__ Wq,
                         const float* __restrict__ Wk,
                         const float* __restrict__ Wv,
                         short* __restrict__ xb, short* __restrict__ wb,
                         float* __restrict__ lsum)
{
    size_t v = (size_t)blockIdx.x * 256 + threadIdx.x;
    const float* src; short* dst; size_t off;
    if (v < 2097152)      { src = x;  dst = xb;           off = v; }
    else if (v < 2359296) { src = Wq; dst = wb;           off = v - 2097152; }
    else if (v < 2621440) { src = Wk; dst = wb + 1048576; off = v - 2359296; }
    else if (v < 2883584) { src = Wv; dst = wb + 2097152; off = v - 2621440; }
    else if (v < 2885632) {                               // zero lsum (8192 f32)
        floatx4 z = {0.f, 0.f, 0.f, 0.f};
        ((floatx4*)lsum)[v - 2883584] = z;
        return;
    } else return;
    floatx4 vv = ((const floatx4*)src)[off];
    short4v s;
#pragma unroll
    for (int e = 0; e < 4; ++e) s[e] = f2bf(vv[e]);
    ((short4v*)dst)[off] = s;
}

// ---------------------------------------------------------------------------
// Kernel 1: QKV projection as ONE 8192x3072x1024 GEMM-BT, 256x256 tile,
// BK=64, 8 waves (2Mx4N), 128 KiB LDS. m201-faithful 8-phase schedule:
// per phase {quadrant ds_reads; stage ONE half-tile (2x gl_lds);
// [lgkmcnt(8) if 12 reads]; bar; lgkmcnt(0); setprio1; 16 MFMA; setprio0;
// bar}. vmcnt(4) ONLY at phases 4 and 8 (2 half-tiles may stay in flight).
//
// Staging map per 8-phase iter (compute kt=S0 ph1-4, kt+1=S1 ph5-8):
//   ph1: S1.A.h0 (kt+1)   [S1.A last read prev-iter ph7; bar-separated]
//   ph2: S1.A.h1 (kt+1)
//   ph3: S0.B.h0 (kt+2)   [S0.B last read ph2]
//   ph4: S0.B.h1 (kt+2)   + vmcnt(4): leaves ph3,4 in flight -> ph1,2 +
//                           prev ph7,8 landed => ph5's S1 reads safe
//   ph5: S0.A.h0 (kt+2)   [S0.A last read ph3]
//   ph6: S0.A.h1 (kt+2)
//   ph7: S1.B.h0 (kt+3)   [S1.B last read ph6]
//   ph8: S1.B.h1 (kt+3)   + vmcnt(4): leaves ph7,8 in flight -> ph3..6
//                           landed => next ph1's S0 reads safe
// ---------------------------------------------------------------------------
struct Q8Ctx {
    const short* Ag; const short* Bg;
    short *A0, *B0, *A1, *B1;
    int srow, scl, scg;          // staging row / LDS col (linear) / global col (pre-swizzled)
    int aB, bB, c0, c1;          // ds_read bases and swizzled col offsets
};

#define LD_AF(SLOT, HI) do { _Pragma("unroll") \
    for (int mi_ = 0; mi_ < 4; ++mi_) { \
        af[mi_][0] = *(const short8*)((SLOT) + X.aB + (HI) + mi_ * 1024 + X.c0); \
        af[mi_][1] = *(const short8*)((SLOT) + X.aB + (HI) + mi_ * 1024 + X.c1); \
    } } while (0)

#define LD_BF(SLOT, N0) do { _Pragma("unroll") \
    for (int ni_ = 0; ni_ < 2; ++ni_) { \
        bf[(N0) + ni_][0] = *(const short8*)((SLOT) + X.bB + ((N0) + ni_) * 1024 + X.c0); \
        bf[(N0) + ni_][1] = *(const short8*)((SLOT) + X.bB + ((N0) + ni_) * 1024 + X.c1); \
    } } while (0)

#define MM_Q(MB, N0) do { _Pragma("unroll") \
    for (int mi_ = 0; mi_ < 4; ++mi_) { _Pragma("unroll") \
        for (int ni_ = 0; ni_ < 2; ++ni_) { \
            acc[(MB)+mi_][(N0)+ni_] = MFMA_BF16(af[mi_][0], bf[(N0)+ni_][0], acc[(MB)+mi_][(N0)+ni_], 0, 0, 0); \
            acc[(MB)+mi_][(N0)+ni_] = MFMA_BF16(af[mi_][1], bf[(N0)+ni_][1], acc[(MB)+mi_][(N0)+ni_], 0, 0, 0); \
        } } } while (0)

#define STAGE_HALF(DST, SRC, KOFS) do { \
    gl_lds16((SRC) + (size_t)(X.srow)      * 1024 + (KOFS) + X.scg, (DST) + (X.srow)      * 64 + X.scl); \
    gl_lds16((SRC) + (size_t)(64 + X.srow) * 1024 + (KOFS) + X.scg, (DST) + (64 + X.srow) * 64 + X.scl); \
    } while (0)

#define BARR  __builtin_amdgcn_s_barrier()
#define WLG0  asm volatile("s_waitcnt lgkmcnt(0)" ::: "memory")
#define WLG8  asm volatile("s_waitcnt lgkmcnt(8)" ::: "memory")
#define PRI1  __builtin_amdgcn_s_setprio(1)
#define PRI0  __builtin_amdgcn_s_setprio(0)

template<bool TAIL>
__device__ __attribute__((always_inline)) inline void iter8(
    const Q8Ctx& X, int kb, floatx4 acc[8][4])
{
    const int sk1 = kb + 64, sk2 = kb + 128, sk3 = kb + 192;
    short8 af[4][2], bf[4][2];

    // ---- ph1: kt q(m-lo,n-lo); 12 reads; stage S1.A.h0
    LD_AF(X.A0, 0); LD_BF(X.B0, 0);
    STAGE_HALF(X.A1, X.Ag, sk1);
    WLG8;
    BARR; WLG0; PRI1; MM_Q(0, 0); PRI0; BARR;
    // ---- ph2: q(m-lo,n-hi); 4 reads; stage S1.A.h1
    LD_BF(X.B0, 2);
    STAGE_HALF(X.A1 + 8192, X.Ag + 131072, sk1);
    BARR; WLG0; PRI1; MM_Q(0, 2); PRI0; BARR;
    // ---- ph3: q(m-hi,n-hi); 8 reads; stage S0.B.h0 (kt+2)
    LD_AF(X.A0, 4096);
    if (!TAIL) STAGE_HALF(X.B0, X.Bg, sk2);
    BARR; WLG0; PRI1; MM_Q(4, 2); PRI0; BARR;
    // ---- ph4: q(m-hi,n-lo); 0 reads; stage S0.B.h1; vmcnt
    if (!TAIL) STAGE_HALF(X.B0 + 8192, X.Bg + 131072, sk2);
    BARR; PRI1; MM_Q(4, 0); PRI0;
    if (!TAIL) asm volatile("s_waitcnt vmcnt(4)" ::: "memory");
    else       asm volatile("s_waitcnt vmcnt(0)" ::: "memory");
    BARR;

    // ---- ph5: kt+1 q(m-lo,n-lo); 12 reads; stage S0.A.h0 (kt+2)
    LD_AF(X.A1, 0); LD_BF(X.B1, 0);
    if (!TAIL) STAGE_HALF(X.A0, X.Ag, sk2);
    WLG8;
    BARR; WLG0; PRI1; MM_Q(0, 0); PRI0; BARR;
    // ---- ph6: q(m-lo,n-hi); 4 reads; stage S0.A.h1 (kt+2)
    LD_BF(X.B1, 2);
    if (!TAIL) STAGE_HALF(X.A0 + 8192, X.Ag + 131072, sk2);
    BARR; WLG0; PRI1; MM_Q(0, 2); PRI0; BARR;
    // ---- ph7: q(m-hi,n-hi); 8 reads; stage S1.B.h0 (kt+3)
    LD_AF(X.A1, 4096);
    if (!TAIL) STAGE_HALF(X.B1, X.Bg, sk3);
    BARR; WLG0; PRI1; MM_Q(4, 2); PRI0; BARR;
    // ---- ph8: q(m-hi,n-lo); 0 reads; stage S1.B.h1; vmcnt
    if (!TAIL) STAGE_HALF(X.B1 + 8192, X.Bg + 131072, sk3);
    BARR; PRI1; MM_Q(4, 0); PRI0;
    if (!TAIL) asm volatile("s_waitcnt vmcnt(4)" ::: "memory");
    BARR;
}

__global__ __launch_bounds__(512, 2) void qkv_gemm8(
    const short* __restrict__ xb, const short* __restrict__ wb,
    short* __restrict__ qb, short* __restrict__ kb, short* __restrict__ vt)
{
    __shared__ short lds[65536];   // 128 KiB: [A0|B0|A1|B1], 32 KiB each

    // XCD-aware swizzle: 384 blocks, 384 % 8 == 0 -> bijective.
    const int orig = blockIdx.x;
    const int tile = (orig & 7) * 48 + (orig >> 3);
    const int mt = tile & 31;
    const int nt = tile >> 5;
    const int m0 = mt * 256;

    const int t    = threadIdx.x;
    const int lane = t & 63;
    const int wid  = t >> 6;
    const int wy   = wid >> 2, wx = wid & 3;
    const int lm   = lane & 15, lq = lane >> 4;

    Q8Ctx X;
    X.Ag = xb + (size_t)m0 * 1024;
    X.Bg = wb + (size_t)(nt * 256) * 1024;
    X.A0 = lds;          X.B0 = lds + 16384;
    X.A1 = lds + 32768;  X.B1 = lds + 49152;
    X.srow = t >> 3;
    X.scl  = (t & 7) * 8;                       // LDS col: linear
    X.scg  = ((t & 7) ^ (X.srow & 7)) * 8;      // global col: pre-swizzled (T2)
    X.c0 = (lq ^ (lm & 7)) * 8;                 // ds_read swizzled k-slot lo
    X.c1 = ((4 + lq) ^ (lm & 7)) * 8;           // hi
    X.aB = (wy * 128 + lm) * 64;
    X.bB = (wx * 64 + lm) * 64;

    floatx4 acc[8][4];
    floatx4 zero = {0.f, 0.f, 0.f, 0.f};
#pragma unroll
    for (int i = 0; i < 8; ++i)
#pragma unroll
        for (int j = 0; j < 4; ++j) acc[i][j] = zero;

    // prologue: stage kt0 (A+B, 8 loads) then kt1.B (4 loads); wait kt0 only.
    STAGE_HALF(X.A0,         X.Ag,          0);
    STAGE_HALF(X.A0 + 8192,  X.Ag + 131072, 0);
    STAGE_HALF(X.B0,         X.Bg,          0);
    STAGE_HALF(X.B0 + 8192,  X.Bg + 131072, 0);
    STAGE_HALF(X.B1,         X.Bg,          64);
    STAGE_HALF(X.B1 + 8192,  X.Bg + 131072, 64);
    asm volatile("s_waitcnt vmcnt(4)" ::: "memory");
    __builtin_amdgcn_s_barrier();

    // 16 K-tiles: 7 full double-iterations + 1 tail.
#pragma unroll 1
    for (int i = 0; i < 7; ++i)
        iter8<false>(X, i * 128, acc);
    iter8<true>(X, 7 * 128, acc);

    // epilogue (unchanged)
    const int nglob = nt * 256;
    const int which = nglob >> 10;          // 0:Q 1:K 2:V (uniform per block)
    const int ncol  = (nglob & 1023) + wx * 64;
#pragma unroll
    for (int mi = 0; mi < 8; ++mi)
#pragma unroll
        for (int r = 0; r < 4; ++r) {
            const int row = m0 + wy * 128 + mi * 16 + lq * 4 + r;
#pragma unroll
            for (int ni = 0; ni < 4; ++ni) {
                const int col = ncol + ni * 16 + lm;
                const short bv = f2bf(acc[mi][ni][r]);
                if (which == 2) {
                    const int bb = row >> 11, tt = row & 2047;
                    vt[((size_t)bb * 1024 + col) * 2048 + tt] = bv;
                } else if (which == 1) {
                    kb[(size_t)row * 1024 + col] = bv;
                } else {
                    qb[(size_t)row * 1024 + col] = bv;
                }
            }
        }
}

// ---------------------------------------------------------------------------
// Kernel 2: fused S = QK^T*scale -> P = exp(S) (bf16, no-max) + causal mask
// + atomic row sums. grid (136 packed (i,j) j<=i, 4 b).
// ---------------------------------------------------------------------------
__global__ __launch_bounds__(256, 3) void sqk_gemm(
    const short* __restrict__ qb, const short* __restrict__ kb,
    short* __restrict__ P, float* __restrict__ lsum)
{
    int idx = blockIdx.x;
    int i = 0;
    while ((i + 1) * (i + 2) / 2 <= idx) ++i;     // decode packed (i,j)
    const int j = idx - i * (i + 1) / 2;
    const int b = blockIdx.y;

    __shared__ short As[128 * 64];
    __shared__ short Bs[128 * 64];

    floatx4 acc[4][4];
    floatx4 zero = {0.f, 0.f, 0.f, 0.f};
#pragma unroll
    for (int a = 0; a < 4; ++a)
#pragma unroll
        for (int c = 0; c < 4; ++c) acc[a][c] = zero;

    gemm_bt_core(qb + ((size_t)(b * 2048 + i * 128)) * 1024,
                 kb + ((size_t)(b * 2048 + j * 128)) * 1024,
                 1024, 1024, 1024, As, Bs, acc);

    const float sscl = 0.03125f * 1.44269504089f;   // C^-0.5 * log2(e)
    const bool  diag = (i == j);
    const int lane = threadIdx.x & 63, wid = threadIdx.x >> 6;
    const int wx = wid & 1, wy = wid >> 1, lm = lane & 15, lq = lane >> 4;

#pragma unroll
    for (int mi = 0; mi < 4; ++mi)
#pragma unroll
        for (int r = 0; r < 4; ++r) {
            const int lrow = wy * 64 + mi * 16 + lq * 4 + r;      // 0..127
            const int grow = i * 128 + lrow;
            short* prow = P + ((size_t)b * 2048 + grow) * 2048 + j * 128;
            float rsum = 0.f;
#pragma unroll
            for (int ni = 0; ni < 4; ++ni) {
                const int lcol = wx * 64 + ni * 16 + lm;
                float p = exp2f(acc[mi][ni][r] * sscl);
                if (diag && lcol > lrow) p = 0.f;                 // causal
                rsum += p;
                prow[lcol] = f2bf(p);
            }
#pragma unroll
            for (int off = 1; off < 16; off <<= 1) rsum += __shfl_xor(rsum, off);
            if (lm == 0) atomicAdd(lsum + b * 2048 + grow, rsum);
        }
}

// ---------------------------------------------------------------------------
// Kernel 3: O = (P V) / l. Causal-balanced pairs (i, 15-i).
// ---------------------------------------------------------------------------
__global__ __launch_bounds__(256, 3) void pv_gemm(
    const short* __restrict__ P, const short* __restrict__ vt,
    const float* __restrict__ lsum, float* __restrict__ out)
{
    const int x  = blockIdx.x;     // 64-wide d tile
    const int pr = blockIdx.y;     // pair id
    const int b  = blockIdx.z;
    const int n0 = x * 64;

    __shared__ short As[128 * 64];
    __shared__ short Bs[64 * 64];

    const int t    = threadIdx.x;
    const int srow = t >> 3;
    const int scol = (t & 7) * 8;
    const int lane = t & 63;
    const int wid  = t >> 6;
    const int wx   = wid & 1, wy = wid >> 1;
    const int lm   = lane & 15, lq = lane >> 4;

    const short* Bg = vt + ((size_t)b * 1024 + n0) * 2048;

#pragma unroll
    for (int phase = 0; phase < 2; ++phase) {
        const int i    = phase ? (15 - pr) : pr;
        const int kmax = (i + 1) * 128;
        const short* Ag = P + ((size_t)b * 2048 + i * 128) * 2048;

        floatx4 acc[4][2];
        floatx4 zero = {0.f, 0.f, 0.f, 0.f};
#pragma unroll
        for (int a = 0; a < 4; ++a)
#pragma unroll
            for (int c = 0; c < 2; ++c) acc[a][c] = zero;

        for (int k0 = 0; k0 < kmax; k0 += 64) {
            __syncthreads();
#pragma unroll
            for (int q = 0; q < 4; ++q)
                gl_lds16(Ag + (size_t)(q * 32 + srow) * 2048 + k0 + scol,
                         As + (q * 32 + srow) * 64 + scol);
#pragma unroll
            for (int q = 0; q < 2; ++q)
                gl_lds16(Bg + (size_t)(q * 32 + srow) * 2048 + k0 + scol,
                         Bs + (q * 32 + srow) * 64 + scol);
            __syncthreads();

#pragma unroll
            for (int ks = 0; ks < 2; ++ks) {
                short8 af[4], bfr[2];
#pragma unroll
                for (int mi = 0; mi < 4; ++mi)
                    af[mi] = *(const short8*)(As + (wy * 64 + mi * 16 + lm) * 64 + ks * 32 + lq * 8);
#pragma unroll
                for (int ni = 0; ni < 2; ++ni)
                    bfr[ni] = *(const short8*)(Bs + (wx * 32 + ni * 16 + lm) * 64 + ks * 32 + lq * 8);
#pragma unroll
                for (int mi = 0; mi < 4; ++mi)
#pragma unroll
                    for (int ni = 0; ni < 2; ++ni)
                        acc[mi][ni] = MFMA_BF16(af[mi], bfr[ni], acc[mi][ni], 0, 0, 0);
            }
        }

#pragma unroll
        for (int mi = 0; mi < 4; ++mi)
#pragma unroll
            for (int r = 0; r < 4; ++r) {
                const int grow = b * 2048 + i * 128 + wy * 64 + mi * 16 + lq * 4 + r;
                const float li = 1.0f / lsum[grow];
#pragma unroll
                for (int ni = 0; ni < 2; ++ni)
                    out[(size_t)grow * 1024 + n0 + wx * 32 + ni * 16 + lm] =
                        acc[mi][ni][r] * li;
            }
    }
}

// ---------------------------------------------------------------------------
extern "C" void kernel_launch(void* const* d_in, const int* in_sizes, int n_in,
                              void* d_out, int out_size, void* d_ws, size_t ws_size,
                              hipStream_t stream)
{
    (void)in_sizes; (void)n_in; (void)out_size; (void)ws_size;
    const float* x  = (const float*)d_in[0];
    const float* Wq = (const float*)d_in[1];
    const float* Wk = (const float*)d_in[2];
    const float* Wv = (const float*)d_in[3];
    float* out = (float*)d_out;

    char* base = (char*)d_ws;
    short* xb   = (short*)(base);                       // 16 MB
    short* wb   = (short*)(base + 16777216);            //  6 MB
    short* qb   = (short*)(base + 23068672);            // 16 MB
    short* kb   = (short*)(base + 39845888);            // 16 MB
    short* vt   = (short*)(base + 56623104);            // 16 MB  [b][d][t]
    short* P    = (short*)(base + 73400320);            // 33.6 MB [b][q][k]
    float* lsum = (float*)(base + 107954176);           // 32 KB

    cast_all<<<11272, 256, 0, stream>>>(x, Wq, Wk, Wv, xb, wb, lsum);
    qkv_gemm8<<<dim3(384), 512, 0, stream>>>(xb, wb, qb, kb, vt);
    sqk_gemm<<<dim3(136, 4), 256, 0, stream>>>(qb, kb, P, lsum);
    pv_gemm<<<dim3(16, 8, 4), 256, 0, stream>>>(P, vt, lsum, out);
}

// Round 5
// 249.472 us; speedup vs baseline: 1.1559x; 1.1325x over previous
//
#include <hip/hip_runtime.h>

typedef __attribute__((ext_vector_type(8))) short  short8;
typedef __attribute__((ext_vector_type(4))) short  short4v;
typedef __attribute__((ext_vector_type(4))) float  floatx4;

__device__ inline short f2bf(float f) {
    union { float f; unsigned u; } v; v.f = f;
    unsigned r = v.u + 0x7fffu + ((v.u >> 16) & 1u);
    return (short)(r >> 16);
}

typedef const __attribute__((address_space(1))) unsigned int* gp1_t;
typedef __attribute__((address_space(3))) unsigned int* lp3_t;

__device__ __attribute__((always_inline)) inline void gl_lds16(const short* g, short* l) {
    __builtin_amdgcn_global_load_lds((gp1_t)g, (lp3_t)l, 16, 0, 0);
}

#define MFMA_BF16 __builtin_amdgcn_mfma_f32_16x16x32_bf16

// ---------------------------------------------------------------------------
// m97-style GEMM-BT core: C[128][128], 256 thr / 4 waves (2x2), BK=64.
//   C[m][n] = sum_k A[m][k] * B[n][k]
// 2-barrier structure; relies on 2-3 co-resident blocks/CU for overlap.
// ---------------------------------------------------------------------------
__device__ __attribute__((always_inline)) inline void gemm_bt_core(
    const short* __restrict__ Ag, const short* __restrict__ Bg,
    int lda, int ldb, int kmax,
    short* As, short* Bs, floatx4 acc[4][4])
{
    const int t    = threadIdx.x;
    const int srow = t >> 3;
    const int scol = (t & 7) * 8;
    const int lane = t & 63;
    const int wid  = t >> 6;
    const int wx   = wid & 1, wy = wid >> 1;
    const int lm   = lane & 15, lq = lane >> 4;

    for (int k0 = 0; k0 < kmax; k0 += 64) {
        __syncthreads();
#pragma unroll
        for (int i = 0; i < 4; ++i) {
            gl_lds16(Ag + (size_t)(i * 32 + srow) * lda + k0 + scol,
                     As + (i * 32 + srow) * 64 + scol);
            gl_lds16(Bg + (size_t)(i * 32 + srow) * ldb + k0 + scol,
                     Bs + (i * 32 + srow) * 64 + scol);
        }
        __syncthreads();

#pragma unroll
        for (int ks = 0; ks < 2; ++ks) {
            short8 af[4], bfr[4];
#pragma unroll
            for (int mi = 0; mi < 4; ++mi)
                af[mi] = *(const short8*)(As + (wy * 64 + mi * 16 + lm) * 64 + ks * 32 + lq * 8);
#pragma unroll
            for (int ni = 0; ni < 4; ++ni)
                bfr[ni] = *(const short8*)(Bs + (wx * 64 + ni * 16 + lm) * 64 + ks * 32 + lq * 8);
#pragma unroll
            for (int mi = 0; mi < 4; ++mi)
#pragma unroll
                for (int ni = 0; ni < 4; ++ni)
                    acc[mi][ni] = MFMA_BF16(af[mi], bfr[ni], acc[mi][ni], 0, 0, 0);
        }
    }
}

// ---------------------------------------------------------------------------
// Kernel 0: fp32 -> bf16 cast of x and W's; also zeros lsum (atomic target).
// ---------------------------------------------------------------------------
__global__ void cast_all(const float* __restrict__ x,
                         const float* __restrict__ Wq,
                         const float* __restrict__ Wk,
                         const float* __restrict__ Wv,
                         short* __restrict__ xb, short* __restrict__ wb,
                         float* __restrict__ lsum)
{
    size_t v = (size_t)blockIdx.x * 256 + threadIdx.x;
    const float* src; short* dst; size_t off;
    if (v < 2097152)      { src = x;  dst = xb;           off = v; }
    else if (v < 2359296) { src = Wq; dst = wb;           off = v - 2097152; }
    else if (v < 2621440) { src = Wk; dst = wb + 1048576; off = v - 2359296; }
    else if (v < 2883584) { src = Wv; dst = wb + 2097152; off = v - 2621440; }
    else if (v < 2885632) {                               // zero lsum (8192 f32)
        floatx4 z = {0.f, 0.f, 0.f, 0.f};
        ((floatx4*)lsum)[v - 2883584] = z;
        return;
    } else return;
    floatx4 vv = ((const floatx4*)src)[off];
    short4v s;
#pragma unroll
    for (int e = 0; e < 4; ++e) s[e] = f2bf(vv[e]);
    ((short4v*)dst)[off] = s;
}

// ---------------------------------------------------------------------------
// Kernel 1: QKV projection, y = x @ W^T. Q,K row-major; V transposed [b][d][t].
// Round-0 structure (2-barrier 128^2 core, 1536 blocks, ~3 blocks/CU).
// ---------------------------------------------------------------------------
__global__ __launch_bounds__(256, 3) void qkv_gemm(
    const short* __restrict__ xb, const short* __restrict__ wb,
    short* __restrict__ qb, short* __restrict__ kb, short* __restrict__ vt)
{
    __shared__ short As[128 * 64];
    __shared__ short Bs[128 * 64];

    const int m0    = blockIdx.x * 128;
    const int which = blockIdx.y >> 3;
    const int n0    = (blockIdx.y & 7) * 128;

    floatx4 acc[4][4];
    floatx4 zero = {0.f, 0.f, 0.f, 0.f};
#pragma unroll
    for (int i = 0; i < 4; ++i)
#pragma unroll
        for (int j = 0; j < 4; ++j) acc[i][j] = zero;

    gemm_bt_core(xb + (size_t)m0 * 1024,
                 wb + (size_t)blockIdx.y * 128 * 1024,
                 1024, 1024, 1024, As, Bs, acc);

    const int lane = threadIdx.x & 63, wid = threadIdx.x >> 6;
    const int wx = wid & 1, wy = wid >> 1, lm = lane & 15, lq = lane >> 4;
#pragma unroll
    for (int mi = 0; mi < 4; ++mi)
#pragma unroll
        for (int ni = 0; ni < 4; ++ni)
#pragma unroll
            for (int r = 0; r < 4; ++r) {
                int row = m0 + wy * 64 + mi * 16 + lq * 4 + r;
                int col = n0 + wx * 64 + ni * 16 + lm;
                short bvv = f2bf(acc[mi][ni][r]);
                if (which == 2) {
                    int bb = row >> 11, tt = row & 2047;
                    vt[((size_t)bb * 1024 + col) * 2048 + tt] = bvv;
                } else if (which == 1) {
                    kb[(size_t)row * 1024 + col] = bvv;
                } else {
                    qb[(size_t)row * 1024 + col] = bvv;
                }
            }
}

// ---------------------------------------------------------------------------
// Kernel 2: fused S = QK^T*scale -> P = exp(S) (bf16, no-max: |s|<~6 so e^s
// is safe; softmax ratio identical) + causal mask + atomic row sums.
// grid (136 packed (i,j) j<=i, 4 b). P row-major [b][q][k], ld 2048.
// ---------------------------------------------------------------------------
__global__ __launch_bounds__(256, 3) void sqk_gemm(
    const short* __restrict__ qb, const short* __restrict__ kb,
    short* __restrict__ P, float* __restrict__ lsum)
{
    int idx = blockIdx.x;
    int i = 0;
    while ((i + 1) * (i + 2) / 2 <= idx) ++i;     // decode packed (i,j)
    const int j = idx - i * (i + 1) / 2;
    const int b = blockIdx.y;

    __shared__ short As[128 * 64];
    __shared__ short Bs[128 * 64];

    floatx4 acc[4][4];
    floatx4 zero = {0.f, 0.f, 0.f, 0.f};
#pragma unroll
    for (int a = 0; a < 4; ++a)
#pragma unroll
        for (int c = 0; c < 4; ++c) acc[a][c] = zero;

    gemm_bt_core(qb + ((size_t)(b * 2048 + i * 128)) * 1024,
                 kb + ((size_t)(b * 2048 + j * 128)) * 1024,
                 1024, 1024, 1024, As, Bs, acc);

    const float sscl = 0.03125f * 1.44269504089f;   // C^-0.5 * log2(e)
    const bool  diag = (i == j);
    const int lane = threadIdx.x & 63, wid = threadIdx.x >> 6;
    const int wx = wid & 1, wy = wid >> 1, lm = lane & 15, lq = lane >> 4;

#pragma unroll
    for (int mi = 0; mi < 4; ++mi)
#pragma unroll
        for (int r = 0; r < 4; ++r) {
            const int lrow = wy * 64 + mi * 16 + lq * 4 + r;      // 0..127
            const int grow = i * 128 + lrow;
            short* prow = P + ((size_t)b * 2048 + grow) * 2048 + j * 128;
            float rsum = 0.f;
#pragma unroll
            for (int ni = 0; ni < 4; ++ni) {
                const int lcol = wx * 64 + ni * 16 + lm;
                float p = exp2f(acc[mi][ni][r] * sscl);
                if (diag && lcol > lrow) p = 0.f;                 // causal
                rsum += p;
                prow[lcol] = f2bf(p);
            }
#pragma unroll
            for (int off = 1; off < 16; off <<= 1) rsum += __shfl_xor(rsum, off);
            if (lm == 0) atomicAdd(lsum + b * 2048 + grow, rsum);
        }
}

// ---------------------------------------------------------------------------
// Kernel 3: O = (P V) / l. 128m x 128d tile via gemm_bt_core
// (acc[4][4] -> 32 MFMA/wave/K-step, double the old 128x64 density).
// One i per block; grid (8 d-tiles, 4 b, 16 zi) with i = 15 - zi so the
// longest blocks (kmax = 2048) dispatch FIRST -> LPT packing, makespan
// ~= 17 units = balanced. 512 blocks, 2-3 co-resident/CU for TLP.
// B = vt (pre-transposed [b][d][t], ld 2048). A = P ([b][q][k], ld 2048).
// Upper-triangle P tiles are never written by sqk (garbage) but
// kmax = (i+1)*128 never reads them.
// ---------------------------------------------------------------------------
__global__ __launch_bounds__(256, 3) void pv_gemm(
    const short* __restrict__ P, const short* __restrict__ vt,
    const float* __restrict__ lsum, float* __restrict__ out)
{
    const int x  = blockIdx.x;            // 128-wide d tile (0..7)
    const int b  = blockIdx.y;            // batch
    const int i  = 15 - blockIdx.z;       // q row-block, longest first
    const int n0 = x * 128;
    const int kmax = (i + 1) * 128;

    __shared__ short As[128 * 64];
    __shared__ short Bs[128 * 64];

    const short* Ag = P  + ((size_t)b * 2048 + i * 128) * 2048;
    const short* Bg = vt + ((size_t)b * 1024 + n0) * 2048;

    floatx4 acc[4][4];
    floatx4 zero = {0.f, 0.f, 0.f, 0.f};
#pragma unroll
    for (int a = 0; a < 4; ++a)
#pragma unroll
        for (int c = 0; c < 4; ++c) acc[a][c] = zero;

    gemm_bt_core(Ag, Bg, 2048, 2048, kmax, As, Bs, acc);

    const int lane = threadIdx.x & 63, wid = threadIdx.x >> 6;
    const int wx = wid & 1, wy = wid >> 1, lm = lane & 15, lq = lane >> 4;

#pragma unroll
    for (int mi = 0; mi < 4; ++mi)
#pragma unroll
        for (int r = 0; r < 4; ++r) {
            const int grow = b * 2048 + i * 128 + wy * 64 + mi * 16 + lq * 4 + r;
            const float li = 1.0f / lsum[grow];
#pragma unroll
            for (int ni = 0; ni < 4; ++ni)
                out[(size_t)grow * 1024 + n0 + wx * 64 + ni * 16 + lm] =
                    acc[mi][ni][r] * li;
        }
}

// ---------------------------------------------------------------------------
extern "C" void kernel_launch(void* const* d_in, const int* in_sizes, int n_in,
                              void* d_out, int out_size, void* d_ws, size_t ws_size,
                              hipStream_t stream)
{
    (void)in_sizes; (void)n_in; (void)out_size; (void)ws_size;
    const float* x  = (const float*)d_in[0];
    const float* Wq = (const float*)d_in[1];
    const float* Wk = (const float*)d_in[2];
    const float* Wv = (const float*)d_in[3];
    float* out = (float*)d_out;

    char* base = (char*)d_ws;
    short* xb   = (short*)(base);                       // 16 MB
    short* wb   = (short*)(base + 16777216);            //  6 MB
    short* qb   = (short*)(base + 23068672);            // 16 MB
    short* kb   = (short*)(base + 39845888);            // 16 MB
    short* vt   = (short*)(base + 56623104);            // 16 MB  [b][d][t]
    short* P    = (short*)(base + 73400320);            // 33.6 MB [b][q][k]
    float* lsum = (float*)(base + 107954176);           // 32 KB

    cast_all<<<11272, 256, 0, stream>>>(x, Wq, Wk, Wv, xb, wb, lsum);
    qkv_gemm<<<dim3(64, 24), 256, 0, stream>>>(xb, wb, qb, kb, vt);
    sqk_gemm<<<dim3(136, 4), 256, 0, stream>>>(qb, kb, P, lsum);
    pv_gemm<<<dim3(8, 4, 16), 256, 0, stream>>>(P, vt, lsum, out);
}